// Round 8
// baseline (1213.059 us; speedup 1.0000x reference)
//
#include <hip/hip_runtime.h>
#include <hip/hip_bf16.h>

// WindowAttention: B_=4096 windows, N=64 tokens, C=256, H=8 heads, hd=32.
// One WG (256 thr, 4 waves) per window; wave owns 2 heads.
// r6-verified algebra: swapped-operand QKV passes, 2-stage shfl_xor butterfly
// fragment transposes, biases as MFMA C-in (k pre-scaled by 1/sqrt(d)).
// Register plan: 3 waves/SIMD (170 total regs) via __launch_bounds__(256,3);
// 256-thr WGs give the 3-wave granularity a 512-thr WG can't.
// LDS = x tile ONLY (33.8 KB); attn_out overlays it after the q-precompute
// (all XB reads done before B1). => 3 WGs/CU, 12 waves/CU.

typedef __attribute__((ext_vector_type(8))) short bf16x8;   // 8 bf16 = 4 VGPR
typedef __attribute__((ext_vector_type(4))) float f32x4;    // MFMA acc

struct alignas(8) us4 { unsigned short x, y, z, w; };

__device__ inline unsigned short f2bf(float f) {
    unsigned u = __builtin_bit_cast(unsigned, f);
    u += 0x7fffu + ((u >> 16) & 1u);
    return (unsigned short)(u >> 16);
}

__device__ inline unsigned pack2(float lo, float hi) {   // dword (lo16, hi16)
    return (unsigned)f2bf(lo) | ((unsigned)f2bf(hi) << 16);
}

__device__ inline f32x4 mfma16(bf16x8 a, bf16x8 b, f32x4 c) {
    return __builtin_amdgcn_mfma_f32_16x16x32_bf16(a, b, c, 0, 0, 0);
}

__device__ inline bf16x8 lds8(const unsigned short* p) {
    return *reinterpret_cast<const bf16x8*>(p);
}

// One butterfly stage: swap lane-bit (distance D) with reg-bit1 of V[0..3].
__device__ inline void bfly_stage(unsigned V[4], int D, bool b) {
    unsigned t0 = (unsigned)__shfl_xor((int)V[0], D);
    unsigned t1 = (unsigned)__shfl_xor((int)V[1], D);
    unsigned t2 = (unsigned)__shfl_xor((int)V[2], D);
    unsigned t3 = (unsigned)__shfl_xor((int)V[3], D);
    V[0] = b ? t2 : V[0];
    V[1] = b ? t3 : V[1];
    V[2] = b ? V[2] : t0;
    V[3] = b ? V[3] : t1;
}

// Full cross-g transpose: T[g1 g0 | w1 w0] = V[g0 w1 | g1 w0]  (r6-verified)
__device__ inline bf16x8 bfly4(unsigned v0, unsigned v1, unsigned v2,
                               unsigned v3, int lane) {
    unsigned V[4] = { v0, v1, v2, v3 };
    bfly_stage(V, 32, (lane & 32) != 0);
    bfly_stage(V, 16, (lane & 16) != 0);
    uint4 r = { V[0], V[1], V[2], V[3] };
    return __builtin_bit_cast(bf16x8, r);
}

// ---------------- prep: weight casts (+k prescale) + dense bias gather ------
__global__ void prep_kernel(const float* __restrict__ qkv_w,
                            const float* __restrict__ proj_w,
                            const float* __restrict__ bias_table,
                            const int*   __restrict__ rel_index,
                            unsigned short* __restrict__ qkv_wb,
                            unsigned short* __restrict__ proj_wb,
                            float* __restrict__ biasF) {
    const float scale = 0.1767766952966369f;   // 1/sqrt(32)
    int stride = gridDim.x * blockDim.x;
    int t0 = blockIdx.x * blockDim.x + threadIdx.x;
    for (int i = t0; i < 768 * 256; i += stride) {
        float w = qkv_w[i];
        int row = i >> 8;
        if (row >= 256 && row < 512) w *= scale;   // k rows pre-scaled
        qkv_wb[i] = f2bf(w);
    }
    for (int i = t0; i < 256 * 256; i += stride) proj_wb[i] = f2bf(proj_w[i]);
    for (int i = t0; i < 8 * 64 * 64; i += stride) {
        int h = i >> 12, rem = i & 4095, m = rem >> 6, n = rem & 63;
        biasF[i] = bias_table[rel_index[m * 64 + n] * 8 + h];
    }
}

// ---------------- fused window attention ------------------------------------
// LDS (ushort units), 16896 us = 33792 B:
//   XB @ 0 : x bf16 [64][264]; attn_out [64][264] OVERLAYS it after B1.
__global__ __launch_bounds__(256, 3) void win_attn_kernel(
    const float* __restrict__ x,
    const float* __restrict__ qkv_b,
    const float* __restrict__ proj_b,
    const unsigned short* __restrict__ qkv_wb,
    const unsigned short* __restrict__ proj_wb,
    const float* __restrict__ biasF,
    float* __restrict__ out)
{
    __shared__ unsigned short sm[16896];
    const int tid  = threadIdx.x;
    const int wid  = tid >> 6;         // 0..3
    const int lane = tid & 63;
    const int r16  = lane & 15;
    const int g    = lane >> 4;
    const int win  = blockIdx.x;
    const f32x4 zero4 = {0.f, 0.f, 0.f, 0.f};

    // ---- stage x -> XB (bf16, rows of 264) ----
    const float* xg = x + (size_t)win * 16384;
#pragma unroll
    for (int i = 0; i < 16; ++i) {
        int flat = i * 1024 + tid * 4;
        float4 v = *reinterpret_cast<const float4*>(xg + flat);
        us4 pk = { f2bf(v.x), f2bf(v.y), f2bf(v.z), f2bf(v.w) };
        *reinterpret_cast<us4*>(&sm[(flat >> 8) * 264 + (flat & 255)]) = pk;
    }
    __syncthreads();                                   // B0: XB ready

    // ---- per-head passes (both heads) -> held fragments ----
    bf16x8 av[2][2][2];   // [h2][dt][ks]
    bf16x8 ak[2][4];      // [h2][key tile]
    bf16x8 bq[2][4];      // [h2][query tile]
#pragma unroll
    for (int h2 = 0; h2 < 2; ++h2) {
        const int head = wid * 2 + h2;

        // v pass (normal: D[token][ch])
        {
            f32x4 acc[4][2];
#pragma unroll
            for (int t = 0; t < 4; ++t)
#pragma unroll
                for (int dt = 0; dt < 2; ++dt) {
                    float vb = qkv_b[512 + (2 * head + dt) * 16 + r16];
                    f32x4 ci = { vb, vb, vb, vb };
                    acc[t][dt] = ci;
                }
#pragma unroll
            for (int ks = 0; ks < 8; ++ks) {
                bf16x8 xf[4];
#pragma unroll
                for (int t = 0; t < 4; ++t)
                    xf[t] = lds8(&sm[(t * 16 + r16) * 264 + ks * 32 + g * 8]);
                bf16x8 w0 = *reinterpret_cast<const bf16x8*>(
                    qkv_wb + ((32 + 2 * head + 0) * 16 + r16) * 256 + ks * 32 + g * 8);
                bf16x8 w1 = *reinterpret_cast<const bf16x8*>(
                    qkv_wb + ((32 + 2 * head + 1) * 16 + r16) * 256 + ks * 32 + g * 8);
#pragma unroll
                for (int t = 0; t < 4; ++t) {
                    acc[t][0] = mfma16(xf[t], w0, acc[t][0]);
                    acc[t][1] = mfma16(xf[t], w1, acc[t][1]);
                }
            }
            unsigned vp[4][2][2];
#pragma unroll
            for (int t = 0; t < 4; ++t)
#pragma unroll
                for (int dt = 0; dt < 2; ++dt) {
                    vp[t][dt][0] = pack2(acc[t][dt][0], acc[t][dt][1]);
                    vp[t][dt][1] = pack2(acc[t][dt][2], acc[t][dt][3]);
                }
#pragma unroll
            for (int dt = 0; dt < 2; ++dt)
#pragma unroll
                for (int ks = 0; ks < 2; ++ks)
                    av[h2][dt][ks] = bfly4(vp[2 * ks][dt][0], vp[2 * ks][dt][1],
                                           vp[2 * ks + 1][dt][0],
                                           vp[2 * ks + 1][dt][1], lane);
        }

        // k pass (swapped: A=Wk, B=x; weights+bias pre-scaled)
        {
            f32x4 acc[4][2];
#pragma unroll
            for (int t = 0; t < 4; ++t)
#pragma unroll
                for (int dt = 0; dt < 2; ++dt) {
                    f32x4 ci;
#pragma unroll
                    for (int j = 0; j < 4; ++j)
                        ci[j] = qkv_b[256 + (2 * head + dt) * 16 + g * 4 + j]
                                * 0.1767766952966369f;
                    acc[t][dt] = ci;
                }
#pragma unroll
            for (int ks = 0; ks < 8; ++ks) {
                bf16x8 xf[4];
#pragma unroll
                for (int t = 0; t < 4; ++t)
                    xf[t] = lds8(&sm[(t * 16 + r16) * 264 + ks * 32 + g * 8]);
                bf16x8 w0 = *reinterpret_cast<const bf16x8*>(
                    qkv_wb + ((16 + 2 * head + 0) * 16 + r16) * 256 + ks * 32 + g * 8);
                bf16x8 w1 = *reinterpret_cast<const bf16x8*>(
                    qkv_wb + ((16 + 2 * head + 1) * 16 + r16) * 256 + ks * 32 + g * 8);
#pragma unroll
                for (int t = 0; t < 4; ++t) {
                    acc[t][0] = mfma16(w0, xf[t], acc[t][0]);
                    acc[t][1] = mfma16(w1, xf[t], acc[t][1]);
                }
            }
#pragma unroll
            for (int t = 0; t < 4; ++t)
                ak[h2][t] = bfly4(pack2(acc[t][0][0], acc[t][0][1]),
                                  pack2(acc[t][0][2], acc[t][0][3]),
                                  pack2(acc[t][1][0], acc[t][1][1]),
                                  pack2(acc[t][1][2], acc[t][1][3]), lane);
        }

        // q pass (swapped: A=Wq, B=x)
        {
            f32x4 acc[4][2];
#pragma unroll
            for (int t = 0; t < 4; ++t)
#pragma unroll
                for (int dt = 0; dt < 2; ++dt) {
                    f32x4 ci;
#pragma unroll
                    for (int j = 0; j < 4; ++j)
                        ci[j] = qkv_b[(2 * head + dt) * 16 + g * 4 + j];
                    acc[t][dt] = ci;
                }
#pragma unroll
            for (int ks = 0; ks < 8; ++ks) {
                bf16x8 xf[4];
#pragma unroll
                for (int t = 0; t < 4; ++t)
                    xf[t] = lds8(&sm[(t * 16 + r16) * 264 + ks * 32 + g * 8]);
                bf16x8 w0 = *reinterpret_cast<const bf16x8*>(
                    qkv_wb + ((2 * head + 0) * 16 + r16) * 256 + ks * 32 + g * 8);
                bf16x8 w1 = *reinterpret_cast<const bf16x8*>(
                    qkv_wb + ((2 * head + 1) * 16 + r16) * 256 + ks * 32 + g * 8);
#pragma unroll
                for (int t = 0; t < 4; ++t) {
                    acc[t][0] = mfma16(w0, xf[t], acc[t][0]);
                    acc[t][1] = mfma16(w1, xf[t], acc[t][1]);
                }
            }
#pragma unroll
            for (int t = 0; t < 4; ++t)
                bq[h2][t] = bfly4(pack2(acc[t][0][0], acc[t][0][1]),
                                  pack2(acc[t][0][2], acc[t][0][3]),
                                  pack2(acc[t][1][0], acc[t][1][1]),
                                  pack2(acc[t][1][2], acc[t][1][3]), lane);
        }
    }
    __syncthreads();                 // B1: ALL XB reads done; AO may overlay

    // ---- attention (both heads): QK^T + bias C-in, softmax, PV -> AO ----
#pragma unroll
    for (int h2 = 0; h2 < 2; ++h2) {
        const int head = wid * 2 + h2;
        const float* bh = biasF + head * 4096;
#pragma unroll
        for (int c = 0; c < 4; ++c) {
            f32x4 stc[4];
#pragma unroll
            for (int rt = 0; rt < 4; ++rt) {
                float4 b4 = *reinterpret_cast<const float4*>(
                    bh + (c * 16 + r16) * 64 + rt * 16 + g * 4);
                f32x4 ci = { b4.x, b4.y, b4.z, b4.w };
                stc[rt] = mfma16(ak[h2][rt], bq[h2][c], ci);
            }
            float mx = -1e30f;
#pragma unroll
            for (int rt = 0; rt < 4; ++rt)
#pragma unroll
                for (int j = 0; j < 4; ++j) mx = fmaxf(mx, stc[rt][j]);
            mx = fmaxf(mx, __shfl_xor(mx, 16));
            mx = fmaxf(mx, __shfl_xor(mx, 32));
            float s = 0.f;
#pragma unroll
            for (int rt = 0; rt < 4; ++rt)
#pragma unroll
                for (int j = 0; j < 4; ++j) {
                    float e = __expf(stc[rt][j] - mx);
                    stc[rt][j] = e;
                    s += e;
                }
            s += __shfl_xor(s, 16);
            s += __shfl_xor(s, 32);
            float inv = 1.f / s;

            unsigned pp[4][2];
#pragma unroll
            for (int rt = 0; rt < 4; ++rt) {
                pp[rt][0] = pack2(stc[rt][0] * inv, stc[rt][1] * inv);
                pp[rt][1] = pack2(stc[rt][2] * inv, stc[rt][3] * inv);
            }
            bf16x8 ap0 = bfly4(pp[0][0], pp[0][1], pp[1][0], pp[1][1], lane);
            bf16x8 ap1 = bfly4(pp[2][0], pp[2][1], pp[3][0], pp[3][1], lane);

#pragma unroll
            for (int dt = 0; dt < 2; ++dt) {
                f32x4 o = mfma16(av[h2][dt][0], ap0, zero4);
                o = mfma16(av[h2][dt][1], ap1, o);
                us4 pk = { f2bf(o[0]), f2bf(o[1]), f2bf(o[2]), f2bf(o[3]) };
                *reinterpret_cast<us4*>(
                    &sm[(c * 16 + r16) * 264 + head * 32 + dt * 16 + g * 4]) = pk;
            }
        }
    }
    __syncthreads();                                   // B2: AO ready

    // ---- proj GEMM: wave owns output cols [64w, 64w+64) ----
    f32x4 c3[4][4];
#pragma unroll
    for (int mt = 0; mt < 4; ++mt)
#pragma unroll
        for (int nt = 0; nt < 4; ++nt) c3[mt][nt] = zero4;
#pragma unroll
    for (int ks = 0; ks < 8; ++ks) {
        bf16x8 a3[4];
#pragma unroll
        for (int mt = 0; mt < 4; ++mt)
            a3[mt] = lds8(&sm[(mt * 16 + r16) * 264 + ks * 32 + g * 8]);
#pragma unroll
        for (int nt = 0; nt < 4; ++nt) {
            bf16x8 b3 = *reinterpret_cast<const bf16x8*>(
                proj_wb + (wid * 64 + nt * 16 + r16) * 256 + ks * 32 + g * 8);
#pragma unroll
            for (int mt = 0; mt < 4; ++mt)
                c3[mt][nt] = mfma16(a3[mt], b3, c3[mt][nt]);
        }
    }
    float* og = out + (size_t)win * 16384;
#pragma unroll
    for (int nt = 0; nt < 4; ++nt) {
        int n = wid * 64 + nt * 16 + r16;
        float pb = proj_b[n];
#pragma unroll
        for (int mt = 0; mt < 4; ++mt)
#pragma unroll
            for (int j = 0; j < 4; ++j)
                og[(size_t)(mt * 16 + g * 4 + j) * 256 + n] = c3[mt][nt][j] + pb;
    }
}

extern "C" void kernel_launch(void* const* d_in, const int* in_sizes, int n_in,
                              void* d_out, int out_size, void* d_ws, size_t ws_size,
                              hipStream_t stream) {
    const float* x          = (const float*)d_in[0];
    const float* qkv_w      = (const float*)d_in[1];
    const float* qkv_b      = (const float*)d_in[2];
    const float* proj_w     = (const float*)d_in[3];
    const float* proj_b     = (const float*)d_in[4];
    const float* bias_table = (const float*)d_in[5];
    const int*   rel_index  = (const int*)d_in[6];

    unsigned short* qkv_wb  = (unsigned short*)d_ws;
    unsigned short* proj_wb = (unsigned short*)((char*)d_ws + 393216);
    float* biasF            = (float*)((char*)d_ws + 524288);

    prep_kernel<<<256, 256, 0, stream>>>(qkv_w, proj_w, bias_table, rel_index,
                                         qkv_wb, proj_wb, biasF);
    win_attn_kernel<<<4096, 256, 0, stream>>>(x, qkv_b, proj_b, qkv_wb, proj_wb,
                                              biasF, (float*)d_out);
}

// Round 9
// 891.039 us; speedup vs baseline: 1.3614x; 1.3614x over previous
//
#include <hip/hip_runtime.h>
#include <hip/hip_bf16.h>

// WindowAttention: B_=4096 windows, N=64 tokens, C=256, H=8 heads, hd=32.
// Split design:
//   prep:   weight casts (+k prescale), dense bias gather          (tiny)
//   fused:  qkv + attention per window, 256 thr, wave = 2 heads
//           SEQUENTIALLY (only one head's frags live at a time),
//           q on demand, LDS = x tile only (33.8 KB), AO -> global ws bf16.
//           Target 3 waves/SIMD (170 regs) via __launch_bounds__(256,3).
//   proj:   out = AO @ proj_w^T + b, one window per WG, 4 WGs/CU.
// All MFMA/butterfly algebra is r6/r7/r8 hardware-verified, unchanged.
// Host-side ws_size check falls back to the proven r1 monolith if the
// workspace can't hold AO (needs 655360 + 134217728 bytes).

typedef __attribute__((ext_vector_type(8))) short bf16x8;   // 8 bf16 = 4 VGPR
typedef __attribute__((ext_vector_type(4))) float f32x4;    // MFMA acc

struct alignas(8) us4 { unsigned short x, y, z, w; };

__device__ inline unsigned short f2bf(float f) {
    unsigned u = __builtin_bit_cast(unsigned, f);
    u += 0x7fffu + ((u >> 16) & 1u);
    return (unsigned short)(u >> 16);
}

__device__ inline unsigned pack2(float lo, float hi) {   // dword (lo16, hi16)
    return (unsigned)f2bf(lo) | ((unsigned)f2bf(hi) << 16);
}

__device__ inline f32x4 mfma16(bf16x8 a, bf16x8 b, f32x4 c) {
    return __builtin_amdgcn_mfma_f32_16x16x32_bf16(a, b, c, 0, 0, 0);
}

__device__ inline bf16x8 lds8(const unsigned short* p) {
    return *reinterpret_cast<const bf16x8*>(p);
}

// One butterfly stage: swap lane-bit (distance D) with reg-bit1 of V[0..3].
__device__ inline void bfly_stage(unsigned V[4], int D, bool b) {
    unsigned t0 = (unsigned)__shfl_xor((int)V[0], D);
    unsigned t1 = (unsigned)__shfl_xor((int)V[1], D);
    unsigned t2 = (unsigned)__shfl_xor((int)V[2], D);
    unsigned t3 = (unsigned)__shfl_xor((int)V[3], D);
    V[0] = b ? t2 : V[0];
    V[1] = b ? t3 : V[1];
    V[2] = b ? V[2] : t0;
    V[3] = b ? V[3] : t1;
}

// Full cross-g transpose: T[g1 g0 | w1 w0] = V[g0 w1 | g1 w0]  (r6-verified)
__device__ inline bf16x8 bfly4(unsigned v0, unsigned v1, unsigned v2,
                               unsigned v3, int lane) {
    unsigned V[4] = { v0, v1, v2, v3 };
    bfly_stage(V, 32, (lane & 32) != 0);
    bfly_stage(V, 16, (lane & 16) != 0);
    uint4 r = { V[0], V[1], V[2], V[3] };
    return __builtin_bit_cast(bf16x8, r);
}

// ---------------- prep ------------------------------------------------------
__global__ void prep_kernel(const float* __restrict__ qkv_w,
                            const float* __restrict__ proj_w,
                            const float* __restrict__ bias_table,
                            const int*   __restrict__ rel_index,
                            unsigned short* __restrict__ qkv_wb,
                            unsigned short* __restrict__ proj_wb,
                            float* __restrict__ biasF) {
    const float scale = 0.1767766952966369f;   // 1/sqrt(32)
    int stride = gridDim.x * blockDim.x;
    int t0 = blockIdx.x * blockDim.x + threadIdx.x;
    for (int i = t0; i < 768 * 256; i += stride) {
        float w = qkv_w[i];
        int row = i >> 8;
        if (row >= 256 && row < 512) w *= scale;   // k rows pre-scaled
        qkv_wb[i] = f2bf(w);
    }
    for (int i = t0; i < 256 * 256; i += stride) proj_wb[i] = f2bf(proj_w[i]);
    for (int i = t0; i < 8 * 64 * 64; i += stride) {
        int h = i >> 12, rem = i & 4095, m = rem >> 6, n = rem & 63;
        biasF[i] = bias_table[rel_index[m * 64 + n] * 8 + h];
    }
}

// ---------------- fused qkv + attention -------------------------------------
// LDS: XB [64][264] bf16 = 33792 B, read-only after B0 (no other barriers).
__global__ __launch_bounds__(256, 3) void qkv_attn_kernel(
    const float* __restrict__ x,
    const float* __restrict__ qkv_b,
    const unsigned short* __restrict__ qkv_wb,
    const float* __restrict__ biasF,
    unsigned short* __restrict__ AOg)
{
    __shared__ unsigned short sm[16896];
    const int tid  = threadIdx.x;
    const int wid  = tid >> 6;         // 0..3
    const int lane = tid & 63;
    const int r16  = lane & 15;
    const int g    = lane >> 4;
    const int win  = blockIdx.x;
    const f32x4 zero4 = {0.f, 0.f, 0.f, 0.f};

    // ---- stage x -> XB ----
    const float* xg = x + (size_t)win * 16384;
#pragma unroll
    for (int i = 0; i < 16; ++i) {
        int flat = i * 1024 + tid * 4;
        float4 v = *reinterpret_cast<const float4*>(xg + flat);
        us4 pk = { f2bf(v.x), f2bf(v.y), f2bf(v.z), f2bf(v.w) };
        *reinterpret_cast<us4*>(&sm[(flat >> 8) * 264 + (flat & 255)]) = pk;
    }
    __syncthreads();                                   // B0: XB ready

    unsigned short* aow = AOg + (size_t)win * 16384;

    for (int h2 = 0; h2 < 2; ++h2) {                   // heads sequential
        const int head = wid * 2 + h2;
        const float* bh = biasF + head * 4096;

        // ---- v pass (normal: D[token][ch]) -> av; all temps die after ----
        bf16x8 av[2][2];
        {
            f32x4 acc[4][2];
#pragma unroll
            for (int t = 0; t < 4; ++t)
#pragma unroll
                for (int dt = 0; dt < 2; ++dt) {
                    float vb = qkv_b[512 + (2 * head + dt) * 16 + r16];
                    f32x4 ci = { vb, vb, vb, vb };
                    acc[t][dt] = ci;
                }
#pragma unroll
            for (int ks = 0; ks < 8; ++ks) {
                bf16x8 xf[4];
#pragma unroll
                for (int t = 0; t < 4; ++t)
                    xf[t] = lds8(&sm[(t * 16 + r16) * 264 + ks * 32 + g * 8]);
                bf16x8 w0 = *reinterpret_cast<const bf16x8*>(
                    qkv_wb + ((32 + 2 * head + 0) * 16 + r16) * 256 + ks * 32 + g * 8);
                bf16x8 w1 = *reinterpret_cast<const bf16x8*>(
                    qkv_wb + ((32 + 2 * head + 1) * 16 + r16) * 256 + ks * 32 + g * 8);
#pragma unroll
                for (int t = 0; t < 4; ++t) {
                    acc[t][0] = mfma16(xf[t], w0, acc[t][0]);
                    acc[t][1] = mfma16(xf[t], w1, acc[t][1]);
                }
            }
            unsigned vp[4][2][2];
#pragma unroll
            for (int t = 0; t < 4; ++t)
#pragma unroll
                for (int dt = 0; dt < 2; ++dt) {
                    vp[t][dt][0] = pack2(acc[t][dt][0], acc[t][dt][1]);
                    vp[t][dt][1] = pack2(acc[t][dt][2], acc[t][dt][3]);
                }
#pragma unroll
            for (int dt = 0; dt < 2; ++dt)
#pragma unroll
                for (int ks = 0; ks < 2; ++ks)
                    av[dt][ks] = bfly4(vp[2 * ks][dt][0], vp[2 * ks][dt][1],
                                       vp[2 * ks + 1][dt][0],
                                       vp[2 * ks + 1][dt][1], lane);
        }

        // ---- k pass (swapped; weights+bias pre-scaled) -> ak ----
        bf16x8 ak[4];
        {
            f32x4 acc[4][2];
#pragma unroll
            for (int t = 0; t < 4; ++t)
#pragma unroll
                for (int dt = 0; dt < 2; ++dt) {
                    f32x4 ci;
#pragma unroll
                    for (int j = 0; j < 4; ++j)
                        ci[j] = qkv_b[256 + (2 * head + dt) * 16 + g * 4 + j]
                                * 0.1767766952966369f;
                    acc[t][dt] = ci;
                }
#pragma unroll
            for (int ks = 0; ks < 8; ++ks) {
                bf16x8 xf[4];
#pragma unroll
                for (int t = 0; t < 4; ++t)
                    xf[t] = lds8(&sm[(t * 16 + r16) * 264 + ks * 32 + g * 8]);
                bf16x8 w0 = *reinterpret_cast<const bf16x8*>(
                    qkv_wb + ((16 + 2 * head + 0) * 16 + r16) * 256 + ks * 32 + g * 8);
                bf16x8 w1 = *reinterpret_cast<const bf16x8*>(
                    qkv_wb + ((16 + 2 * head + 1) * 16 + r16) * 256 + ks * 32 + g * 8);
#pragma unroll
                for (int t = 0; t < 4; ++t) {
                    acc[t][0] = mfma16(w0, xf[t], acc[t][0]);
                    acc[t][1] = mfma16(w1, xf[t], acc[t][1]);
                }
            }
#pragma unroll
            for (int t = 0; t < 4; ++t)
                ak[t] = bfly4(pack2(acc[t][0][0], acc[t][0][1]),
                              pack2(acc[t][0][2], acc[t][0][3]),
                              pack2(acc[t][1][0], acc[t][1][1]),
                              pack2(acc[t][1][2], acc[t][1][3]), lane);
        }

        // ---- attention per query tile: q on demand (r7-verified) ----
#pragma unroll
        for (int c = 0; c < 4; ++c) {
            f32x4 qa[2];
#pragma unroll
            for (int dt = 0; dt < 2; ++dt) {
                f32x4 ci;
#pragma unroll
                for (int j = 0; j < 4; ++j)
                    ci[j] = qkv_b[(2 * head + dt) * 16 + g * 4 + j];
                qa[dt] = ci;
            }
#pragma unroll
            for (int ks = 0; ks < 8; ++ks) {
                bf16x8 xf = lds8(&sm[(c * 16 + r16) * 264 + ks * 32 + g * 8]);
                bf16x8 w0 = *reinterpret_cast<const bf16x8*>(
                    qkv_wb + ((2 * head + 0) * 16 + r16) * 256 + ks * 32 + g * 8);
                bf16x8 w1 = *reinterpret_cast<const bf16x8*>(
                    qkv_wb + ((2 * head + 1) * 16 + r16) * 256 + ks * 32 + g * 8);
                qa[0] = mfma16(w0, xf, qa[0]);
                qa[1] = mfma16(w1, xf, qa[1]);
            }
            bf16x8 bqc = bfly4(pack2(qa[0][0], qa[0][1]),
                               pack2(qa[0][2], qa[0][3]),
                               pack2(qa[1][0], qa[1][1]),
                               pack2(qa[1][2], qa[1][3]), lane);

            f32x4 stc[4];
#pragma unroll
            for (int rt = 0; rt < 4; ++rt) {
                float4 b4 = *reinterpret_cast<const float4*>(
                    bh + (c * 16 + r16) * 64 + rt * 16 + g * 4);
                f32x4 ci = { b4.x, b4.y, b4.z, b4.w };
                stc[rt] = mfma16(ak[rt], bqc, ci);
            }
            float mx = -1e30f;
#pragma unroll
            for (int rt = 0; rt < 4; ++rt)
#pragma unroll
                for (int j = 0; j < 4; ++j) mx = fmaxf(mx, stc[rt][j]);
            mx = fmaxf(mx, __shfl_xor(mx, 16));
            mx = fmaxf(mx, __shfl_xor(mx, 32));
            float s = 0.f;
#pragma unroll
            for (int rt = 0; rt < 4; ++rt)
#pragma unroll
                for (int j = 0; j < 4; ++j) {
                    float e = __expf(stc[rt][j] - mx);
                    stc[rt][j] = e;
                    s += e;
                }
            s += __shfl_xor(s, 16);
            s += __shfl_xor(s, 32);
            float inv = 1.f / s;

            unsigned pp[4][2];
#pragma unroll
            for (int rt = 0; rt < 4; ++rt) {
                pp[rt][0] = pack2(stc[rt][0] * inv, stc[rt][1] * inv);
                pp[rt][1] = pack2(stc[rt][2] * inv, stc[rt][3] * inv);
            }
            bf16x8 ap0 = bfly4(pp[0][0], pp[0][1], pp[1][0], pp[1][1], lane);
            bf16x8 ap1 = bfly4(pp[2][0], pp[2][1], pp[3][0], pp[3][1], lane);

#pragma unroll
            for (int dt = 0; dt < 2; ++dt) {
                f32x4 o = mfma16(av[dt][0], ap0, zero4);
                o = mfma16(av[dt][1], ap1, o);
                us4 pk = { f2bf(o[0]), f2bf(o[1]), f2bf(o[2]), f2bf(o[3]) };
                *reinterpret_cast<us4*>(
                    &aow[(c * 16 + r16) * 256 + head * 32 + dt * 16 + g * 4]) = pk;
            }
        }
    }
}

// ---------------- proj GEMM: out = AO @ proj_w^T + b ------------------------
// One window per WG; LDS 33.8 KB; 4 WGs/CU.  (r8 phase-3 algebra, verified.)
__global__ __launch_bounds__(256, 4) void proj_kernel(
    const unsigned short* __restrict__ AOg,
    const unsigned short* __restrict__ proj_wb,
    const float* __restrict__ proj_b,
    float* __restrict__ out)
{
    __shared__ unsigned short sm[16896];
    const int tid  = threadIdx.x;
    const int wid  = tid >> 6;
    const int lane = tid & 63;
    const int r16  = lane & 15;
    const int g    = lane >> 4;
    const int win  = blockIdx.x;
    const f32x4 zero4 = {0.f, 0.f, 0.f, 0.f};

    const unsigned short* aor = AOg + (size_t)win * 16384;
#pragma unroll
    for (int i = 0; i < 8; ++i) {
        int flat = i * 2048 + tid * 8;     // ushort units, 16B per thread
        *reinterpret_cast<uint4*>(&sm[(flat >> 8) * 264 + (flat & 255)]) =
            *reinterpret_cast<const uint4*>(&aor[flat]);
    }
    __syncthreads();

    f32x4 c3[4][4];
#pragma unroll
    for (int mt = 0; mt < 4; ++mt)
#pragma unroll
        for (int nt = 0; nt < 4; ++nt) c3[mt][nt] = zero4;
#pragma unroll
    for (int ks = 0; ks < 8; ++ks) {
        bf16x8 a3[4];
#pragma unroll
        for (int mt = 0; mt < 4; ++mt)
            a3[mt] = lds8(&sm[(mt * 16 + r16) * 264 + ks * 32 + g * 8]);
#pragma unroll
        for (int nt = 0; nt < 4; ++nt) {
            bf16x8 b3 = *reinterpret_cast<const bf16x8*>(
                proj_wb + (wid * 64 + nt * 16 + r16) * 256 + ks * 32 + g * 8);
#pragma unroll
            for (int mt = 0; mt < 4; ++mt)
                c3[mt][nt] = mfma16(a3[mt], b3, c3[mt][nt]);
        }
    }
    float* og = out + (size_t)win * 16384;
#pragma unroll
    for (int nt = 0; nt < 4; ++nt) {
        int n = wid * 64 + nt * 16 + r16;
        float pb = proj_b[n];
#pragma unroll
        for (int mt = 0; mt < 4; ++mt)
#pragma unroll
            for (int j = 0; j < 4; ++j)
                og[(size_t)(mt * 16 + g * 4 + j) * 256 + n] = c3[mt][nt][j] + pb;
    }
}

// ---------------- fallback: proven r1 monolith (426 us) ---------------------
__global__ __launch_bounds__(512, 2) void win_attn_fallback(
    const float* __restrict__ x,
    const float* __restrict__ qkv_b,
    const float* __restrict__ proj_b,
    const unsigned short* __restrict__ qkv_wb,
    const unsigned short* __restrict__ proj_wb,
    const float* __restrict__ biasF,
    float* __restrict__ out)
{
    __shared__ unsigned short sm[76288];
    const int tid  = threadIdx.x;
    const int wid  = tid >> 6;
    const int lane = tid & 63;
    const int r16  = lane & 15;
    const int g    = lane >> 4;
    const int win  = blockIdx.x;
    const float* xg = x + (size_t)win * 16384;

#pragma unroll
    for (int i = 0; i < 8; ++i) {
        int flat = i * 2048 + tid * 4;
        float4 v = *reinterpret_cast<const float4*>(xg + flat);
        int row = flat >> 8, col = flat & 255;
        us4 pk = { f2bf(v.x), f2bf(v.y), f2bf(v.z), f2bf(v.w) };
        *reinterpret_cast<us4*>(&sm[row * 264 + col]) = pk;
    }
    __syncthreads();

    const int h = wid;
    int ntb[6];
    ntb[0] = 2 * h;      ntb[1] = 2 * h + 1;
    ntb[2] = 16 + 2 * h; ntb[3] = 17 + 2 * h;
    ntb[4] = 32 + 2 * h; ntb[5] = 33 + 2 * h;

    const f32x4 zero4 = {0.f, 0.f, 0.f, 0.f};
    f32x4 acc[4][6];
#pragma unroll
    for (int a = 0; a < 4; ++a)
#pragma unroll
        for (int b = 0; b < 6; ++b) acc[a][b] = zero4;

#pragma unroll
    for (int ks = 0; ks < 8; ++ks) {
        bf16x8 af[4];
#pragma unroll
        for (int mt = 0; mt < 4; ++mt)
            af[mt] = lds8(&sm[(mt * 16 + r16) * 264 + ks * 32 + g * 8]);
#pragma unroll
        for (int ni = 0; ni < 6; ++ni) {
            const unsigned short* wp =
                qkv_wb + (ntb[ni] * 16 + r16) * 256 + ks * 32 + g * 8;
            bf16x8 bf = *reinterpret_cast<const bf16x8*>(wp);
#pragma unroll
            for (int mt = 0; mt < 4; ++mt)
                acc[mt][ni] = mfma16(af[mt], bf, acc[mt][ni]);
        }
    }

    const int qbase = 16896 + h * 5120;
    const int kbase = qbase + 2560;
    const int vtb   = 57856 + h * 2304;
    const float scale = 0.1767766952966369f;

#pragma unroll
    for (int ni = 0; ni < 6; ++ni) {
        int n = ntb[ni] * 16 + r16;
        float qb = qkv_b[n];
        int d = (ni & 1) * 16 + r16;
#pragma unroll
        for (int mt = 0; mt < 4; ++mt) {
            f32x4 a4 = acc[mt][ni];
            if (ni < 2) {
#pragma unroll
                for (int j = 0; j < 4; ++j)
                    sm[qbase + (mt * 16 + g * 4 + j) * 40 + d] = f2bf(a4[j] + qb);
            } else if (ni < 4) {
#pragma unroll
                for (int j = 0; j < 4; ++j)
                    sm[kbase + (mt * 16 + g * 4 + j) * 40 + d] =
                        f2bf((a4[j] + qb) * scale);
            } else {
                us4 pk = { f2bf(a4[0] + qb), f2bf(a4[1] + qb),
                           f2bf(a4[2] + qb), f2bf(a4[3] + qb) };
                *reinterpret_cast<us4*>(&sm[vtb + d * 72 + mt * 16 + g * 4]) = pk;
            }
        }
    }
    __syncthreads();

    bf16x8 ak[4], bq[4];
#pragma unroll
    for (int t = 0; t < 4; ++t) {
        ak[t] = lds8(&sm[kbase + (t * 16 + r16) * 40 + g * 8]);
        bq[t] = lds8(&sm[qbase + (t * 16 + r16) * 40 + g * 8]);
    }
    f32x4 st[4][4];
    const float* bh = biasF + h * 4096;
#pragma unroll
    for (int rt = 0; rt < 4; ++rt)
#pragma unroll
        for (int ct = 0; ct < 4; ++ct) {
            float4 b4 = *reinterpret_cast<const float4*>(
                bh + (ct * 16 + r16) * 64 + rt * 16 + g * 4);
            f32x4 ci = { b4.x, b4.y, b4.z, b4.w };
            st[rt][ct] = mfma16(ak[rt], bq[ct], ci);
        }

#pragma unroll
    for (int ct = 0; ct < 4; ++ct) {
        int m = ct * 16 + r16;
        float pv[4][4];
        float mx = -1e30f;
#pragma unroll
        for (int rt = 0; rt < 4; ++rt)
#pragma unroll
            for (int j = 0; j < 4; ++j) {
                float v = st[rt][ct][j];
                pv[rt][j] = v;
                mx = fmaxf(mx, v);
            }
        mx = fmaxf(mx, __shfl_xor(mx, 16));
        mx = fmaxf(mx, __shfl_xor(mx, 32));
        float s = 0.f;
#pragma unroll
        for (int rt = 0; rt < 4; ++rt)
#pragma unroll
            for (int j = 0; j < 4; ++j) {
                float e = __expf(pv[rt][j] - mx);
                pv[rt][j] = e;
                s += e;
            }
        s += __shfl_xor(s, 16);
        s += __shfl_xor(s, 32);
        float inv = 1.f / s;
#pragma unroll
        for (int rt = 0; rt < 4; ++rt) {
            us4 pk = { f2bf(pv[rt][0] * inv), f2bf(pv[rt][1] * inv),
                       f2bf(pv[rt][2] * inv), f2bf(pv[rt][3] * inv) };
            *reinterpret_cast<us4*>(&sm[qbase + m * 72 + rt * 16 + g * 4]) = pk;
        }
    }
    asm volatile("s_waitcnt lgkmcnt(0)" ::: "memory");

    f32x4 o[4][2];
#pragma unroll
    for (int mt = 0; mt < 4; ++mt)
#pragma unroll
        for (int nt = 0; nt < 2; ++nt) o[mt][nt] = zero4;
#pragma unroll
    for (int ks = 0; ks < 2; ++ks) {
        bf16x8 ap[4];
#pragma unroll
        for (int mt = 0; mt < 4; ++mt)
            ap[mt] = lds8(&sm[qbase + (mt * 16 + r16) * 72 + ks * 32 + g * 8]);
#pragma unroll
        for (int nt = 0; nt < 2; ++nt) {
            bf16x8 bv = lds8(&sm[vtb + (nt * 16 + r16) * 72 + ks * 32 + g * 8]);
#pragma unroll
            for (int mt = 0; mt < 4; ++mt)
                o[mt][nt] = mfma16(ap[mt], bv, o[mt][nt]);
        }
    }
#pragma unroll
    for (int mt = 0; mt < 4; ++mt)
#pragma unroll
        for (int nt = 0; nt < 2; ++nt)
#pragma unroll
            for (int j = 0; j < 4; ++j)
                sm[(mt * 16 + g * 4 + j) * 264 + h * 32 + nt * 16 + r16] =
                    f2bf(o[mt][nt][j]);
    __syncthreads();

    f32x4 c3[4][2];
#pragma unroll
    for (int mt = 0; mt < 4; ++mt)
#pragma unroll
        for (int nt = 0; nt < 2; ++nt) c3[mt][nt] = zero4;
#pragma unroll
    for (int ks = 0; ks < 8; ++ks) {
        bf16x8 a3[4];
#pragma unroll
        for (int mt = 0; mt < 4; ++mt)
            a3[mt] = lds8(&sm[(mt * 16 + r16) * 264 + ks * 32 + g * 8]);
#pragma unroll
        for (int nt = 0; nt < 2; ++nt) {
            const unsigned short* wp =
                proj_wb + (wid * 32 + nt * 16 + r16) * 256 + ks * 32 + g * 8;
            bf16x8 b3 = *reinterpret_cast<const bf16x8*>(wp);
#pragma unroll
            for (int mt = 0; mt < 4; ++mt)
                c3[mt][nt] = mfma16(a3[mt], b3, c3[mt][nt]);
        }
    }
    float* og = out + (size_t)win * 16384;
#pragma unroll
    for (int nt = 0; nt < 2; ++nt) {
        int n = wid * 32 + nt * 16 + r16;
        float pb = proj_b[n];
#pragma unroll
        for (int mt = 0; mt < 4; ++mt)
#pragma unroll
            for (int j = 0; j < 4; ++j)
                og[(size_t)(mt * 16 + g * 4 + j) * 256 + n] = c3[mt][nt][j] + pb;
    }
}

extern "C" void kernel_launch(void* const* d_in, const int* in_sizes, int n_in,
                              void* d_out, int out_size, void* d_ws, size_t ws_size,
                              hipStream_t stream) {
    const float* x          = (const float*)d_in[0];
    const float* qkv_w      = (const float*)d_in[1];
    const float* qkv_b      = (const float*)d_in[2];
    const float* proj_w     = (const float*)d_in[3];
    const float* proj_b     = (const float*)d_in[4];
    const float* bias_table = (const float*)d_in[5];
    const int*   rel_index  = (const int*)d_in[6];

    unsigned short* qkv_wb  = (unsigned short*)d_ws;
    unsigned short* proj_wb = (unsigned short*)((char*)d_ws + 393216);
    float* biasF            = (float*)((char*)d_ws + 524288);
    unsigned short* AOg     = (unsigned short*)((char*)d_ws + 655360);

    prep_kernel<<<256, 256, 0, stream>>>(qkv_w, proj_w, bias_table, rel_index,
                                         qkv_wb, proj_wb, biasF);

    const size_t need = 655360ull + 4096ull * 64 * 256 * 2;   // +AO bf16
    if (ws_size >= need) {
        qkv_attn_kernel<<<4096, 256, 0, stream>>>(x, qkv_b, qkv_wb, biasF, AOg);
        proj_kernel<<<4096, 256, 0, stream>>>(AOg, proj_wb, proj_b,
                                              (float*)d_out);
    } else {
        win_attn_fallback<<<4096, 512, 0, stream>>>(x, qkv_b, proj_b, qkv_wb,
                                                    proj_wb, biasF,
                                                    (float*)d_out);
    }
}